// Round 2
// baseline (565.582 us; speedup 1.0000x reference)
//
#include <hip/hip_runtime.h>

// SelfAttnPool: B=32, T=4096, F=512, U=512 (fp32 in/out)
//   scores[b,t] = tanh(x[b,t,:]@W + b) @ V   (u never materialized)
//   a = softmax_T(scores); out[b,f] = sum_t a[b,t]*x[b,t,f]
//
// R6: occupancy-driven restructure. R5 post-mortem: 1 block/CU (232 regs/wave),
// 8 waves lockstep -> loads serialize with MFMA (MfmaUtil 30%). Now each block
// runs FOUR sequential 32-row GEMM sub-passes (acc 32 AGPR instead of 128);
// waves split U 8-ways (64 cols each). Target <=128 regs/wave -> 2 blocks/CU
// (4 waves/SIMD from independent blocks) so barrier phases decorrelate.
// Chunk stays 128 rows: softmax/pooling/partial/combine identical to R5.
// Cost: W re-streamed per sub (4GB L2 total, under the 34.5 TB/s ceiling).

#define XT 4096
#define XF 512
#define XU 512

typedef __attribute__((ext_vector_type(8))) short short8;
typedef __attribute__((ext_vector_type(4))) short sh4;
typedef __attribute__((ext_vector_type(16))) float f32x16;

__device__ inline void cvt_hilo(float x, unsigned short &h, unsigned short &l) {
  unsigned u = __builtin_bit_cast(unsigned, x);
  h = (unsigned short)(u >> 16);                       // truncated bf16 hi
  float hf = __builtin_bit_cast(float, u & 0xFFFF0000u);
  float lo = x - hf;                                   // exact residual
  l = (unsigned short)(__builtin_bit_cast(unsigned, lo) >> 16);
}

__device__ inline float tanh_fast(float z) {
  float e = __expf(2.0f * z);
  return 1.0f - 2.0f * __builtin_amdgcn_rcpf(e + 1.0f);
}

// ---- W pre-conversion: fp32 [512 k][512 n] -> bf16 hi/lo, fragment-ready:
// whi/wlo: [slice s(32)][chunk16B: t(16)*64 + g(2)*32 + l(32)][j(8)]
// element = W[k = s*16 + g*8 + j][n = t*32 + l]
__global__ void wconv_kernel(const float *__restrict__ W,
                             unsigned short *__restrict__ whi,
                             unsigned short *__restrict__ wlo) {
  int t2 = blockIdx.x * 256 + threadIdx.x;  // 32768 threads
  int l = t2 & 31;
  int g = (t2 >> 5) & 1;
  int t = (t2 >> 6) & 15;
  int s = t2 >> 10;
  short8 hv, lv;
#pragma unroll
  for (int j = 0; j < 8; ++j) {
    unsigned short h, lo;
    cvt_hilo(W[(size_t)(s * 16 + g * 8 + j) * XU + t * 32 + l], h, lo);
    hv[j] = (short)h;
    lv[j] = (short)lo;
  }
  size_t off = (size_t)s * 8192 + t * 512 + g * 256 + l * 8;
  *(short8 *)(whi + off) = hv;
  *(short8 *)(wlo + off) = lv;
}

#define MFMA(a, b, c) __builtin_amdgcn_mfma_f32_32x32x16_bf16(a, b, c, 0, 0, 0)

// ---- fused GEMM + tanh + (.@V) + chunk-local softmax + weighted pooling
// block: 512 thr = 8 waves; chunk 128 rows processed as 4x 32-row GEMM subs.
// Wave w owns cols [w*64, w*64+64). acc per wave-sub: 32x64 -> f32x16[2].
__global__ __launch_bounds__(512, 4)
void gemm_scores_kernel(const float *__restrict__ x,
                        const unsigned short *__restrict__ whi,
                        const unsigned short *__restrict__ wlo,
                        const float *__restrict__ bias,
                        const float *__restrict__ V,
                        float *__restrict__ partial,
                        float *__restrict__ pstats) {
  // A staging: per buf 64-k slice of 32 rows: [s16(4)][hi/lo(2)][512 ushort]
  // within a 512-block: idx = g*256 + row*8 + j  (g = (k&15)>>3, j = k&7)
  // -> wave frag read at ushort (s16*1024 + hl*512 + lane*8) is lane-linear.
  __shared__ unsigned short Abuf[2][4096];  // 16 KB
  __shared__ float scb[256];   // [wave 8][row 32] per-wave col-slice scores
  __shared__ float sarr[128];  // chunk scores
  __shared__ float warr[128];  // chunk-local softmax weights e^{s-m}
  __shared__ float red[1536];  // pooling cross-rowgroup reduction

  const int tid = threadIdx.x;
  const int lane = tid & 63;
  const int w = tid >> 6;     // column slice 0..7 (64 cols)
  const int l31 = lane & 31;
  const int half = lane >> 5;
  const size_t rowbase = (size_t)blockIdx.x * 128;

  // staging map: thread -> (row 0..31, k-quad 0..15) of the 32x64 x slice
  const int srow = tid >> 4;
  const int q = tid & 15;
  const int widx = (q >> 2) * 1024 + ((q >> 1) & 1) * 256 + srow * 8 + (q & 1) * 4;

  auto stage = [&](unsigned short *ab, float4 v) {
    sh4 h, l;
    unsigned short hh, ll;
    cvt_hilo(v.x, hh, ll); h[0] = (short)hh; l[0] = (short)ll;
    cvt_hilo(v.y, hh, ll); h[1] = (short)hh; l[1] = (short)ll;
    cvt_hilo(v.z, hh, ll); h[2] = (short)hh; l[2] = (short)ll;
    cvt_hilo(v.w, hh, ll); h[3] = (short)hh; l[3] = (short)ll;
    *(sh4 *)(ab + widx) = h;
    *(sh4 *)(ab + widx + 512) = l;
  };

  const unsigned short *whp = whi + (size_t)(w * 2) * 512 + lane * 8;
  const unsigned short *wlp = wlo + (size_t)(w * 2) * 512 + lane * 8;

#pragma unroll 1
  for (int sub = 0; sub < 4; ++sub) {
    f32x16 acc[2];
#pragma unroll
    for (int c = 0; c < 2; ++c)
#pragma unroll
      for (int r = 0; r < 16; ++r) acc[c][r] = 0.f;

    const float *sx = x + (rowbase + sub * 32 + srow) * XF + q * 4;

    // prologue: stage k-slice 0
    float4 xa = *(const float4 *)sx;
    stage(&Abuf[0][0], xa);
    __syncthreads();

#pragma unroll 1
    for (int it = 0; it < 8; ++it) {
      float4 xn;
      if (it < 7) xn = *(const float4 *)(sx + (it + 1) * 64);  // issue early

      const unsigned short *abase = &Abuf[it & 1][0];
      const unsigned short *pw = whp + (size_t)it * 32768;
      const unsigned short *pl = wlp + (size_t)it * 32768;

#pragma unroll 2
      for (int s16 = 0; s16 < 4; ++s16) {
        short8 bh0 = *(const short8 *)(pw + s16 * 8192);
        short8 bh1 = *(const short8 *)(pw + s16 * 8192 + 512);
        short8 bl0 = *(const short8 *)(pl + s16 * 8192);
        short8 bl1 = *(const short8 *)(pl + s16 * 8192 + 512);
        short8 ah = *(const short8 *)(abase + s16 * 1024 + lane * 8);
        short8 al = *(const short8 *)(abase + s16 * 1024 + 512 + lane * 8);
        // per-acc order hh, lh, hl (matches R5 numerics)
        acc[0] = MFMA(ah, bh0, acc[0]);
        acc[1] = MFMA(ah, bh1, acc[1]);
        acc[0] = MFMA(al, bh0, acc[0]);
        acc[1] = MFMA(al, bh1, acc[1]);
        acc[0] = MFMA(ah, bl0, acc[0]);
        acc[1] = MFMA(ah, bl1, acc[1]);
      }

      if (it < 7) stage(&Abuf[(it + 1) & 1][0], xn);
      __syncthreads();  // nothing vmem-outstanding here: no drain cost
    }

    // ---- sub epilogue: sc[row] = sum over this wave's 64 cols
    // C/D 32x32: col n = w*64 + cf*32 + l31 ; row = (r&3)+8*(r>>2)+4*half
    float sc[16];
#pragma unroll
    for (int r = 0; r < 16; ++r) sc[r] = 0.f;
#pragma unroll
    for (int cf = 0; cf < 2; ++cf) {
      int n = w * 64 + cf * 32 + l31;
      float vv = V[n];
      float bb = bias[n];
#pragma unroll
      for (int r = 0; r < 16; ++r)
        sc[r] += tanh_fast(acc[cf][r] + bb) * vv;
    }
#pragma unroll
    for (int m = 1; m <= 16; m <<= 1) {
#pragma unroll
      for (int r = 0; r < 16; ++r) sc[r] += __shfl_xor(sc[r], m, 64);
    }
    if (l31 == 0) {
#pragma unroll
      for (int r = 0; r < 16; ++r) {
        int row = (r & 3) + 8 * (r >> 2) + 4 * half;
        scb[w * 32 + row] = sc[r];
      }
    }
    __syncthreads();
    if (tid < 32) {
      float s = 0.f;
#pragma unroll
      for (int ww = 0; ww < 8; ++ww) s += scb[ww * 32 + tid];
      sarr[sub * 32 + tid] = s;
    }
    __syncthreads();  // scb/Abuf safe to reuse next sub
  }

  // ---- chunk-local softmax over 128 rows
  float mloc = -1e30f;
#pragma unroll 8
  for (int i = 0; i < 128; ++i) mloc = fmaxf(mloc, sarr[i]);
  if (tid < 128) warr[tid] = __expf(sarr[tid] - mloc);
  __syncthreads();

  // l_c = sum warr : 64-lane shuffle reduce
  float lsum = 0.f;
  if (tid < 64) {
    lsum = warr[tid] + warr[tid + 64];
#pragma unroll
    for (int m = 1; m < 64; m <<= 1) lsum += __shfl_xor(lsum, m, 64);
  }

  // ---- weighted pooling over own (L2-hot) tile: 4 row-groups x 128 col4s
  const int rg = tid >> 7;   // 0..3 -> rows rg*32..+32
  const int c4 = tid & 127;  // float4 column
  const float *xp = x + rowbase * XF;
  float4 pa = {0.f, 0.f, 0.f, 0.f};
#pragma unroll 8
  for (int i = 0; i < 32; ++i) {
    int r = rg * 32 + i;
    float4 v = *(const float4 *)(xp + (size_t)r * XF + c4 * 4);
    float wv = warr[r];
    pa.x += wv * v.x;
    pa.y += wv * v.y;
    pa.z += wv * v.z;
    pa.w += wv * v.w;
  }
  if (rg > 0) {
    float *rp = red + (rg - 1) * 512 + c4 * 4;
    rp[0] = pa.x; rp[1] = pa.y; rp[2] = pa.z; rp[3] = pa.w;
  }
  __syncthreads();
  if (rg == 0) {
    const float *r0 = red + c4 * 4;
    float4 o;
    o.x = pa.x + r0[0] + r0[512] + r0[1024];
    o.y = pa.y + r0[1] + r0[513] + r0[1025];
    o.z = pa.z + r0[2] + r0[514] + r0[1026];
    o.w = pa.w + r0[3] + r0[515] + r0[1027];
    *(float4 *)(partial + (size_t)blockIdx.x * 512 + c4 * 4) = o;
  }
  if (tid == 0) {
    pstats[blockIdx.x * 2] = mloc;
    pstats[blockIdx.x * 2 + 1] = lsum;
  }
}

// ---- combine: out[b,f] = sum_c e^{m_c-M} partial[c][f] / (sum_c e^{m_c-M} l_c)
__global__ __launch_bounds__(512)
void combine_kernel(const float *__restrict__ partial,
                    const float *__restrict__ pstats,
                    float *__restrict__ out) {
  int b = blockIdx.x;
  int f = threadIdx.x;
  __shared__ float ml[32], ll[32];
  if (f < 32) {
    ml[f] = pstats[(b * 32 + f) * 2];
    ll[f] = pstats[(b * 32 + f) * 2 + 1];
  }
  __syncthreads();
  float M = -1e30f;
#pragma unroll
  for (int c = 0; c < 32; ++c) M = fmaxf(M, ml[c]);
  float L = 0.f;
#pragma unroll
  for (int c = 0; c < 32; ++c) L += __expf(ml[c] - M) * ll[c];
  float acc = 0.f;
#pragma unroll
  for (int c = 0; c < 32; ++c)
    acc += __expf(ml[c] - M) * partial[(size_t)(b * 32 + c) * 512 + f];
  out[b * XF + f] = acc / L;
}

extern "C" void kernel_launch(void *const *d_in, const int *in_sizes, int n_in,
                              void *d_out, int out_size, void *d_ws,
                              size_t ws_size, hipStream_t stream) {
  const float *x = (const float *)d_in[0];
  const float *W = (const float *)d_in[1];
  const float *bias = (const float *)d_in[2];
  const float *V = (const float *)d_in[3];
  float *out = (float *)d_out;

  // workspace: whi 512KB | wlo 512KB | partial 2MB | pstats 8KB
  unsigned short *whi = (unsigned short *)d_ws;
  unsigned short *wlo = whi + 262144;
  float *partial = (float *)((char *)d_ws + 1048576);
  float *pstats = (float *)((char *)d_ws + 1048576 + 2097152);

  wconv_kernel<<<128, 256, 0, stream>>>(W, whi, wlo);
  gemm_scores_kernel<<<1024, 512, 0, stream>>>(x, whi, wlo, bias, V, partial,
                                               pstats);
  combine_kernel<<<32, 512, 0, stream>>>(partial, pstats, out);
}

// Round 3
// 527.658 us; speedup vs baseline: 1.0719x; 1.0719x over previous
//
#include <hip/hip_runtime.h>

// SelfAttnPool: B=32, T=4096, F=512, U=512 (fp32 in/out)
//   scores[b,t] = tanh(x[b,t,:]@W + b) @ V   (u never materialized)
//   a = softmax_T(scores); out[b,f] = sum_t a[b,t]*x[b,t,f]
//
// R7: B through LDS, A in registers. R6 post-mortem: occupancy without
// B-reuse lost (4GB L2 B-traffic, 27% MfmaUtil). Now: 8 waves = 4 row-strips
// x 2 col-halves (32 rows x 256 cols each, acc = 128, B-reuse 4x). B k-slice
// (64KB: 2 k16 x hi/lo) double-buffered in LDS, staged via regs with loads
// issued a full step ahead (barrier vmcnt-drain is then free). ONE barrier
// per K32-step (16 total). A rows owned per-wave: converted once, no A-LDS.
// B L2 traffic 1MB/block = 1GB total. Frag ds_reads lane-linear b128 (0
// conflicts); staging writes 16B/thread (2-way, free).
// Numerics: same cvt_hilo + same per-acc term order (hh,lh,hl; k asc).

#define XT 4096
#define XF 512
#define XU 512

typedef __attribute__((ext_vector_type(8))) short short8;
typedef __attribute__((ext_vector_type(16))) float f32x16;

__device__ inline void cvt_hilo(float x, unsigned short &h, unsigned short &l) {
  unsigned u = __builtin_bit_cast(unsigned, x);
  h = (unsigned short)(u >> 16);                       // truncated bf16 hi
  float hf = __builtin_bit_cast(float, u & 0xFFFF0000u);
  float lo = x - hf;                                   // exact residual
  l = (unsigned short)(__builtin_bit_cast(unsigned, lo) >> 16);
}

__device__ inline float tanh_fast(float z) {
  float e = __expf(2.0f * z);
  return 1.0f - 2.0f * __builtin_amdgcn_rcpf(e + 1.0f);
}

// ---- W pre-conversion: fp32 [512 k][512 n] -> bf16 hi/lo, fragment-ready:
// whi/wlo: [slice s(32)][chunk16B: t(16)*64 + g(2)*32 + l(32)][j(8)]
// element = W[k = s*16 + g*8 + j][n = t*32 + l]
__global__ void wconv_kernel(const float *__restrict__ W,
                             unsigned short *__restrict__ whi,
                             unsigned short *__restrict__ wlo) {
  int t2 = blockIdx.x * 256 + threadIdx.x;  // 32768 threads
  int l = t2 & 31;
  int g = (t2 >> 5) & 1;
  int t = (t2 >> 6) & 15;
  int s = t2 >> 10;
  short8 hv, lv;
#pragma unroll
  for (int j = 0; j < 8; ++j) {
    unsigned short h, lo;
    cvt_hilo(W[(size_t)(s * 16 + g * 8 + j) * XU + t * 32 + l], h, lo);
    hv[j] = (short)h;
    lv[j] = (short)lo;
  }
  size_t off = (size_t)s * 8192 + t * 512 + g * 256 + l * 8;
  *(short8 *)(whi + off) = hv;
  *(short8 *)(wlo + off) = lv;
}

#define MFMA(a, b, c) __builtin_amdgcn_mfma_f32_32x32x16_bf16(a, b, c, 0, 0, 0)

// ---- fused GEMM + tanh + (.@V) + chunk-local softmax + weighted pooling
// block: 512 thr = 8 waves; tile 128 rows x 512 cols.
// wave = (rs 0..3, c 0..1): rows rs*32..+32, cols c*256..+256.
__global__ __launch_bounds__(512, 2)
void gemm_scores_kernel(const float *__restrict__ x,
                        const unsigned short *__restrict__ whi,
                        const unsigned short *__restrict__ wlo,
                        const float *__restrict__ bias,
                        const float *__restrict__ V,
                        float *__restrict__ partial,
                        float *__restrict__ pstats) {
  // B staging: per buf, one K32 slice: 4 regions x 8192 ushorts
  // region r = h*2 + hl (h = k16 half, hl = hi/lo), layout = wconv slice
  // layout: [t(16)*512 + g(2)*256 + l(32)*8 + j]. 128 KB total.
  __shared__ unsigned short Bsh[2][4][8192];
  __shared__ float scb[256];   // [c 2][row 128] col-half scores
  __shared__ float sarr[128];  // chunk scores
  __shared__ float warr[128];  // chunk-local softmax weights e^{s-m}
  __shared__ float red[1536];  // pooling cross-rowgroup reduction

  const int tid = threadIdx.x;
  const int lane = tid & 63;
  const int wave = tid >> 6;
  const int rs = wave & 3;    // row strip (32 rows)
  const int c = wave >> 2;    // col half (256 cols)
  const int l31 = lane & 31;
  const int half = lane >> 5;
  const size_t rowbase = (size_t)blockIdx.x * 128;

  f32x16 acc[8];
#pragma unroll
  for (int cf = 0; cf < 8; ++cf)
#pragma unroll
    for (int r = 0; r < 16; ++r) acc[cf][r] = 0.f;

  // A: row = rowbase + rs*32 + l31 ; k = j*32 + h*16 + half*8 + jj
  const float *xr = x + (rowbase + rs * 32 + l31) * XF + half * 8;
  const int toff = tid * 8;                 // staging ushort offset
  const int fbase = (c * 8) * 512 + lane * 8;  // frag ushort offset in region

  short8 st0, st1, st2, st3, st4, st5, st6, st7;
  float4 xa0, xa1, xa2, xa3;

#define LOADSTG(J)                                                   \
  {                                                                  \
    const unsigned short *ph = whi + (size_t)(2 * (J)) * 8192;       \
    const unsigned short *pl = wlo + (size_t)(2 * (J)) * 8192;       \
    st0 = *(const short8 *)(ph + toff);                              \
    st1 = *(const short8 *)(ph + 4096 + toff);                       \
    st2 = *(const short8 *)(pl + toff);                              \
    st3 = *(const short8 *)(pl + 4096 + toff);                       \
    st4 = *(const short8 *)(ph + 8192 + toff);                       \
    st5 = *(const short8 *)(ph + 12288 + toff);                      \
    st6 = *(const short8 *)(pl + 8192 + toff);                       \
    st7 = *(const short8 *)(pl + 12288 + toff);                      \
  }
#define WRITESTG(BUF)                                                \
  {                                                                  \
    unsigned short *d = &Bsh[BUF][0][0] + toff;                      \
    *(short8 *)(d) = st0;                                            \
    *(short8 *)(d + 4096) = st1;                                     \
    *(short8 *)(d + 8192) = st2;                                     \
    *(short8 *)(d + 12288) = st3;                                    \
    *(short8 *)(d + 16384) = st4;                                    \
    *(short8 *)(d + 20480) = st5;                                    \
    *(short8 *)(d + 24576) = st6;                                    \
    *(short8 *)(d + 28672) = st7;                                    \
  }
#define LOADA(J)                                                     \
  {                                                                  \
    xa0 = *(const float4 *)(xr + (J) * 32);                          \
    xa1 = *(const float4 *)(xr + (J) * 32 + 4);                      \
    xa2 = *(const float4 *)(xr + (J) * 32 + 16);                     \
    xa3 = *(const float4 *)(xr + (J) * 32 + 20);                     \
  }

  // ---- prologue: stage step 0, load A step 0
  LOADSTG(0);
  LOADA(0);
  WRITESTG(0);
  __syncthreads();

#pragma unroll 1
  for (int j = 0; j < 16; ++j) {
    const int cur = j & 1;

    // convert current A (loaded last iter; vmcnt drained at barrier)
    short8 ah0, al0, ah1, al1;
    {
      float v0[8] = {xa0.x, xa0.y, xa0.z, xa0.w, xa1.x, xa1.y, xa1.z, xa1.w};
      float v1[8] = {xa2.x, xa2.y, xa2.z, xa2.w, xa3.x, xa3.y, xa3.z, xa3.w};
#pragma unroll
      for (int jj = 0; jj < 8; ++jj) {
        unsigned short h, lo;
        cvt_hilo(v0[jj], h, lo);
        ah0[jj] = (short)h; al0[jj] = (short)lo;
        cvt_hilo(v1[jj], h, lo);
        ah1[jj] = (short)h; al1[jj] = (short)lo;
      }
    }

    // issue next-step staging + A loads (complete during this step's MFMAs)
    if (j < 15) {
      LOADSTG(j + 1);
      LOADA(j + 1);
    }

    // compute from buf[cur]
#pragma unroll
    for (int h = 0; h < 2; ++h) {
      const unsigned short *bp = &Bsh[cur][h * 2][0] + fbase;
      const unsigned short *lp = bp + 8192;
      short8 ahf = h ? ah1 : ah0;
      short8 alf = h ? al1 : al0;
#pragma unroll
      for (int cf = 0; cf < 8; ++cf) {
        short8 bh = *(const short8 *)(bp + cf * 512);
        short8 bl = *(const short8 *)(lp + cf * 512);
        acc[cf] = MFMA(ahf, bh, acc[cf]);
        acc[cf] = MFMA(alf, bh, acc[cf]);
        acc[cf] = MFMA(ahf, bl, acc[cf]);
      }
    }

    if (j < 15) WRITESTG(cur ^ 1);
    __syncthreads();
  }

  // ---- score epilogue: sc[row] = sum over this wave's 256 cols
  // C/D 32x32: col n = c*256 + cf*32 + l31 ; row = (r&3)+8*(r>>2)+4*half
  float sc[16];
#pragma unroll
  for (int r = 0; r < 16; ++r) sc[r] = 0.f;
#pragma unroll
  for (int cf = 0; cf < 8; ++cf) {
    int n = c * 256 + cf * 32 + l31;
    float vv = V[n];
    float bb = bias[n];
#pragma unroll
    for (int r = 0; r < 16; ++r)
      sc[r] += tanh_fast(acc[cf][r] + bb) * vv;
  }
#pragma unroll
  for (int m = 1; m <= 16; m <<= 1) {
#pragma unroll
    for (int r = 0; r < 16; ++r) sc[r] += __shfl_xor(sc[r], m, 64);
  }
  if (l31 == 0) {
#pragma unroll
    for (int r = 0; r < 16; ++r) {
      int row = rs * 32 + (r & 3) + 8 * (r >> 2) + 4 * half;
      scb[c * 128 + row] = sc[r];
    }
  }
  __syncthreads();

  // ---- chunk-local softmax over 128 rows
  if (tid < 128) sarr[tid] = scb[tid] + scb[128 + tid];
  __syncthreads();
  float mloc = -1e30f;
#pragma unroll 8
  for (int i = 0; i < 128; ++i) mloc = fmaxf(mloc, sarr[i]);
  if (tid < 128) warr[tid] = __expf(sarr[tid] - mloc);
  __syncthreads();

  // l_c = sum warr : 64-lane shuffle reduce
  float lsum = 0.f;
  if (tid < 64) {
    lsum = warr[tid] + warr[tid + 64];
#pragma unroll
    for (int m = 1; m < 64; m <<= 1) lsum += __shfl_xor(lsum, m, 64);
  }

  // ---- weighted pooling over own (L2-hot) tile: 4 row-groups x 128 col4s
  const int rg = tid >> 7;   // 0..3 -> rows rg*32..+32
  const int c4 = tid & 127;  // float4 column
  const float *xp = x + rowbase * XF;
  float4 pa = {0.f, 0.f, 0.f, 0.f};
#pragma unroll 8
  for (int i = 0; i < 32; ++i) {
    int r = rg * 32 + i;
    float4 v = *(const float4 *)(xp + (size_t)r * XF + c4 * 4);
    float wv = warr[r];
    pa.x += wv * v.x;
    pa.y += wv * v.y;
    pa.z += wv * v.z;
    pa.w += wv * v.w;
  }
  if (rg > 0) {
    float *rp = red + (rg - 1) * 512 + c4 * 4;
    rp[0] = pa.x; rp[1] = pa.y; rp[2] = pa.z; rp[3] = pa.w;
  }
  __syncthreads();
  if (rg == 0) {
    const float *r0 = red + c4 * 4;
    float4 o;
    o.x = pa.x + r0[0] + r0[512] + r0[1024];
    o.y = pa.y + r0[1] + r0[513] + r0[1025];
    o.z = pa.z + r0[2] + r0[514] + r0[1026];
    o.w = pa.w + r0[3] + r0[515] + r0[1027];
    *(float4 *)(partial + (size_t)blockIdx.x * 512 + c4 * 4) = o;
  }
  if (tid == 0) {
    pstats[blockIdx.x * 2] = mloc;
    pstats[blockIdx.x * 2 + 1] = lsum;
  }
}

// ---- combine: out[b,f] = sum_c e^{m_c-M} partial[c][f] / (sum_c e^{m_c-M} l_c)
__global__ __launch_bounds__(512)
void combine_kernel(const float *__restrict__ partial,
                    const float *__restrict__ pstats,
                    float *__restrict__ out) {
  int b = blockIdx.x;
  int f = threadIdx.x;
  __shared__ float ml[32], ll[32];
  if (f < 32) {
    ml[f] = pstats[(b * 32 + f) * 2];
    ll[f] = pstats[(b * 32 + f) * 2 + 1];
  }
  __syncthreads();
  float M = -1e30f;
#pragma unroll
  for (int c = 0; c < 32; ++c) M = fmaxf(M, ml[c]);
  float L = 0.f;
#pragma unroll
  for (int c = 0; c < 32; ++c) L += __expf(ml[c] - M) * ll[c];
  float acc = 0.f;
#pragma unroll
  for (int c = 0; c < 32; ++c)
    acc += __expf(ml[c] - M) * partial[(size_t)(b * 32 + c) * 512 + f];
  out[b * XF + f] = acc / L;
}

extern "C" void kernel_launch(void *const *d_in, const int *in_sizes, int n_in,
                              void *d_out, int out_size, void *d_ws,
                              size_t ws_size, hipStream_t stream) {
  const float *x = (const float *)d_in[0];
  const float *W = (const float *)d_in[1];
  const float *bias = (const float *)d_in[2];
  const float *V = (const float *)d_in[3];
  float *out = (float *)d_out;

  // workspace: whi 512KB | wlo 512KB | partial 2MB | pstats 8KB
  unsigned short *whi = (unsigned short *)d_ws;
  unsigned short *wlo = whi + 262144;
  float *partial = (float *)((char *)d_ws + 1048576);
  float *pstats = (float *)((char *)d_ws + 1048576 + 2097152);

  wconv_kernel<<<128, 256, 0, stream>>>(W, whi, wlo);
  gemm_scores_kernel<<<1024, 512, 0, stream>>>(x, whi, wlo, bias, V, partial,
                                               pstats);
  combine_kernel<<<32, 512, 0, stream>>>(partial, pstats, out);
}